// Round 1
// baseline (171.083 us; speedup 1.0000x reference)
//
#include <hip/hip_runtime.h>
#include <hip/hip_bf16.h>

#define N_TOK 2048
#define DMODEL 1024
#define NHEAD 16
#define DHEAD 64
#define LN_EPS 1e-5f

typedef __attribute__((ext_vector_type(8))) short short8;
typedef __attribute__((ext_vector_type(4))) float f32x4;

__device__ inline unsigned short f2bf(float f) {
    union { float f; unsigned u; } v; v.f = f;
    unsigned r = v.u + 0x7FFF + ((v.u >> 16) & 1);
    return (unsigned short)(r >> 16);
}

// ---------------- convert f32 -> bf16 ----------------
__global__ void cvt_f32_bf16(const float* __restrict__ in, unsigned short* __restrict__ out) {
    int i = (blockIdx.x * blockDim.x + threadIdx.x) * 4;
    float4 v = *reinterpret_cast<const float4*>(in + i);
    ushort4 o;
    o.x = f2bf(v.x); o.y = f2bf(v.y); o.z = f2bf(v.z); o.w = f2bf(v.w);
    *reinterpret_cast<ushort4*>(out + i) = o;
}

__global__ void cvt_w(const float* __restrict__ w0, const float* __restrict__ w1,
                      const float* __restrict__ w2, const float* __restrict__ w3,
                      unsigned short* __restrict__ o0, unsigned short* __restrict__ o1,
                      unsigned short* __restrict__ o2, unsigned short* __restrict__ o3) {
    int z = blockIdx.y;
    const float* in = z == 0 ? w0 : (z == 1 ? w1 : (z == 2 ? w2 : w3));
    unsigned short* out = z == 0 ? o0 : (z == 1 ? o1 : (z == 2 ? o2 : o3));
    int i = (blockIdx.x * blockDim.x + threadIdx.x) * 4;
    float4 v = *reinterpret_cast<const float4*>(in + i);
    ushort4 o;
    o.x = f2bf(v.x); o.y = f2bf(v.y); o.z = f2bf(v.z); o.w = f2bf(v.w);
    *reinterpret_cast<ushort4*>(out + i) = o;
}

// ---------------- fused QKV GEMM ----------------
// O = X @ W^T + b ; X:[2048,1024] bf16, W:[1024,1024] bf16 row-major (K inner)
// grid (16, 24): bn 0..7 -> Q, 8..15 -> K, 16..23 -> V
#define BM 128
#define BN 128
#define BK 64
#define LDP 72

__global__ __launch_bounds__(256) void gemm_qkv(
    const unsigned short* __restrict__ X,
    const unsigned short* __restrict__ Wq, const unsigned short* __restrict__ Wk,
    const unsigned short* __restrict__ Wv,
    const float* __restrict__ bq, const float* __restrict__ bk, const float* __restrict__ bv,
    unsigned short* __restrict__ Q, unsigned short* __restrict__ K, unsigned short* __restrict__ V)
{
    __shared__ __align__(16) unsigned short As[BM][LDP];
    __shared__ __align__(16) unsigned short Bs[BN][LDP];
    int row0 = blockIdx.x * BM;
    int col0 = blockIdx.y * BN;          // 0..3071
    int mat = col0 >> 10;
    int wcol0 = col0 & 1023;
    const unsigned short* W = mat == 0 ? Wq : (mat == 1 ? Wk : Wv);
    const float* bias = mat == 0 ? bq : (mat == 1 ? bk : bv);
    unsigned short* Obuf = mat == 0 ? Q : (mat == 1 ? K : V);

    int t = threadIdx.x;
    int w = t >> 6, l = t & 63;
    int lr = l & 15, lk = l >> 4;
    int wr = (w >> 1) * 64, wc = (w & 1) * 64;

    f32x4 acc[4][4] = {};

    for (int k0 = 0; k0 < DMODEL; k0 += BK) {
        #pragma unroll
        for (int it = 0; it < 4; ++it) {
            int c = it * 256 + t;          // 0..1023
            int r = c >> 3, cw = c & 7;
            short8 av = *reinterpret_cast<const short8*>(X + (size_t)(row0 + r) * DMODEL + k0 + cw * 8);
            *reinterpret_cast<short8*>(&As[r][cw * 8]) = av;
            short8 bv8 = *reinterpret_cast<const short8*>(W + (size_t)(wcol0 + r) * DMODEL + k0 + cw * 8);
            *reinterpret_cast<short8*>(&Bs[r][cw * 8]) = bv8;
        }
        __syncthreads();
        #pragma unroll
        for (int kk = 0; kk < BK; kk += 32) {
            short8 af[4], bf[4];
            #pragma unroll
            for (int m = 0; m < 4; ++m)
                af[m] = *reinterpret_cast<const short8*>(&As[wr + m * 16 + lr][kk + lk * 8]);
            #pragma unroll
            for (int n = 0; n < 4; ++n)
                bf[n] = *reinterpret_cast<const short8*>(&Bs[wc + n * 16 + lr][kk + lk * 8]);
            #pragma unroll
            for (int m = 0; m < 4; ++m)
                #pragma unroll
                for (int n = 0; n < 4; ++n)
                    acc[m][n] = __builtin_amdgcn_mfma_f32_16x16x32_bf16(af[m], bf[n], acc[m][n], 0, 0, 0);
        }
        __syncthreads();
    }

    #pragma unroll
    for (int n = 0; n < 4; ++n) {
        int ccol = wcol0 + wc + n * 16 + lr;
        float bia = bias[ccol];
        #pragma unroll
        for (int m = 0; m < 4; ++m) {
            #pragma unroll
            for (int r = 0; r < 4; ++r) {
                int rowg = row0 + wr + m * 16 + lk * 4 + r;
                Obuf[(size_t)rowg * DMODEL + ccol] = f2bf(acc[m][n][r] + bia);
            }
        }
    }
}

// ---------------- flash attention ----------------
// grid (32, 16): blockIdx.x = q block (64 rows), blockIdx.y = head
__global__ __launch_bounds__(256) void attn(
    const unsigned short* __restrict__ Q, const unsigned short* __restrict__ K,
    const unsigned short* __restrict__ V, const float* __restrict__ mask,
    unsigned short* __restrict__ Ctx)
{
    __shared__ __align__(16) unsigned short Kt[64][LDP];
    __shared__ __align__(16) unsigned short Vt[64][LDP];   // transposed: Vt[dh][kv]
    __shared__ __align__(16) unsigned short Ps[4][16][LDP];

    int h = blockIdx.y;
    int q0 = blockIdx.x * 64;
    int t = threadIdx.x, w = t >> 6, l = t & 63;
    int lr = l & 15, lk = l >> 4;

    short8 qf[2];
    #pragma unroll
    for (int kk = 0; kk < 2; ++kk)
        qf[kk] = *reinterpret_cast<const short8*>(
            Q + (size_t)(q0 + w * 16 + lr) * DMODEL + h * DHEAD + kk * 32 + lk * 8);

    f32x4 ctx[4] = {};
    float mrow[4], lsum[4];
    #pragma unroll
    for (int r = 0; r < 4; ++r) { mrow[r] = -1e30f; lsum[r] = 0.f; }

    for (int kt = 0; kt < N_TOK / 64; ++kt) {
        int k0 = kt * 64;
        #pragma unroll
        for (int it = 0; it < 2; ++it) {
            int cc = it * 256 + t;       // 0..511
            int r = cc >> 3, cw = cc & 7;
            short8 kv8 = *reinterpret_cast<const short8*>(
                K + (size_t)(k0 + r) * DMODEL + h * DHEAD + cw * 8);
            *reinterpret_cast<short8*>(&Kt[r][cw * 8]) = kv8;
            short8 vv = *reinterpret_cast<const short8*>(
                V + (size_t)(k0 + r) * DMODEL + h * DHEAD + cw * 8);
            #pragma unroll
            for (int j = 0; j < 8; ++j)
                Vt[cw * 8 + j][r] = (unsigned short)vv[j];
        }
        __syncthreads();

        // S = (Q K^T) * 0.125 + mask
        f32x4 s[4];
        #pragma unroll
        for (int n = 0; n < 4; ++n) {
            f32x4 z = {};
            #pragma unroll
            for (int kk = 0; kk < 2; ++kk) {
                short8 bf8 = *reinterpret_cast<const short8*>(&Kt[n * 16 + lr][kk * 32 + lk * 8]);
                z = __builtin_amdgcn_mfma_f32_16x16x32_bf16(qf[kk], bf8, z, 0, 0, 0);
            }
            s[n] = z;
        }
        float tmax[4];
        #pragma unroll
        for (int r = 0; r < 4; ++r) tmax[r] = -1e30f;
        #pragma unroll
        for (int n = 0; n < 4; ++n) {
            float madd = (1.0f - mask[k0 + n * 16 + lr]) * -10000.0f;
            #pragma unroll
            for (int r = 0; r < 4; ++r) {
                s[n][r] = s[n][r] * 0.125f + madd;
                tmax[r] = fmaxf(tmax[r], s[n][r]);
            }
        }
        #pragma unroll
        for (int d = 1; d < 16; d <<= 1)
            #pragma unroll
            for (int r = 0; r < 4; ++r)
                tmax[r] = fmaxf(tmax[r], __shfl_xor(tmax[r], d));
        float psum[4];
        #pragma unroll
        for (int r = 0; r < 4; ++r) {
            float mnew = fmaxf(mrow[r], tmax[r]);
            float scale = __expf(mrow[r] - mnew);
            mrow[r] = mnew;
            lsum[r] *= scale;
            #pragma unroll
            for (int n = 0; n < 4; ++n) ctx[n][r] *= scale;
            psum[r] = 0.f;
        }
        #pragma unroll
        for (int n = 0; n < 4; ++n) {
            #pragma unroll
            for (int r = 0; r < 4; ++r) {
                float p = __expf(s[n][r] - mrow[r]);
                psum[r] += p;
                Ps[w][lk * 4 + r][n * 16 + lr] = f2bf(p);
            }
        }
        #pragma unroll
        for (int d = 1; d < 16; d <<= 1)
            #pragma unroll
            for (int r = 0; r < 4; ++r)
                psum[r] += __shfl_xor(psum[r], d);
        #pragma unroll
        for (int r = 0; r < 4; ++r) lsum[r] += psum[r];

        // ctx += P @ V
        #pragma unroll
        for (int n = 0; n < 4; ++n) {
            #pragma unroll
            for (int kk = 0; kk < 2; ++kk) {
                short8 pa = *reinterpret_cast<const short8*>(&Ps[w][lr][kk * 32 + lk * 8]);
                short8 vb = *reinterpret_cast<const short8*>(&Vt[n * 16 + lr][kk * 32 + lk * 8]);
                ctx[n] = __builtin_amdgcn_mfma_f32_16x16x32_bf16(pa, vb, ctx[n], 0, 0, 0);
            }
        }
        __syncthreads();
    }

    #pragma unroll
    for (int n = 0; n < 4; ++n) {
        #pragma unroll
        for (int r = 0; r < 4; ++r) {
            float v = ctx[n][r] / lsum[r];
            Ctx[(size_t)(q0 + w * 16 + lk * 4 + r) * DMODEL + h * DHEAD + n * 16 + lr] = f2bf(v);
        }
    }
}

// ---------------- dense + tanh + residual ----------------
// Sht = tanh(Ctx @ Wd^T + bd) + ht ; grid (16, 8)
__global__ __launch_bounds__(256) void gemm_dense(
    const unsigned short* __restrict__ X, const unsigned short* __restrict__ W,
    const float* __restrict__ bias, const float* __restrict__ ht,
    float* __restrict__ Sht)
{
    __shared__ __align__(16) unsigned short As[BM][LDP];
    __shared__ __align__(16) unsigned short Bs[BN][LDP];
    int row0 = blockIdx.x * BM;
    int col0 = blockIdx.y * BN;

    int t = threadIdx.x;
    int w = t >> 6, l = t & 63;
    int lr = l & 15, lk = l >> 4;
    int wr = (w >> 1) * 64, wc = (w & 1) * 64;

    f32x4 acc[4][4] = {};

    for (int k0 = 0; k0 < DMODEL; k0 += BK) {
        #pragma unroll
        for (int it = 0; it < 4; ++it) {
            int c = it * 256 + t;
            int r = c >> 3, cw = c & 7;
            short8 av = *reinterpret_cast<const short8*>(X + (size_t)(row0 + r) * DMODEL + k0 + cw * 8);
            *reinterpret_cast<short8*>(&As[r][cw * 8]) = av;
            short8 bv8 = *reinterpret_cast<const short8*>(W + (size_t)(col0 + r) * DMODEL + k0 + cw * 8);
            *reinterpret_cast<short8*>(&Bs[r][cw * 8]) = bv8;
        }
        __syncthreads();
        #pragma unroll
        for (int kk = 0; kk < BK; kk += 32) {
            short8 af[4], bf[4];
            #pragma unroll
            for (int m = 0; m < 4; ++m)
                af[m] = *reinterpret_cast<const short8*>(&As[wr + m * 16 + lr][kk + lk * 8]);
            #pragma unroll
            for (int n = 0; n < 4; ++n)
                bf[n] = *reinterpret_cast<const short8*>(&Bs[wc + n * 16 + lr][kk + lk * 8]);
            #pragma unroll
            for (int m = 0; m < 4; ++m)
                #pragma unroll
                for (int n = 0; n < 4; ++n)
                    acc[m][n] = __builtin_amdgcn_mfma_f32_16x16x32_bf16(af[m], bf[n], acc[m][n], 0, 0, 0);
        }
        __syncthreads();
    }

    #pragma unroll
    for (int n = 0; n < 4; ++n) {
        int col = col0 + wc + n * 16 + lr;
        float bia = bias[col];
        #pragma unroll
        for (int m = 0; m < 4; ++m) {
            #pragma unroll
            for (int r = 0; r < 4; ++r) {
                int rowg = row0 + wr + m * 16 + lk * 4 + r;
                float val = tanhf(acc[m][n][r] + bia) + ht[(size_t)rowg * DMODEL + col];
                Sht[(size_t)rowg * DMODEL + col] = val;
            }
        }
    }
}

// ---------------- layernorm ----------------
__global__ __launch_bounds__(256) void layernorm(
    const float* __restrict__ S, const float* __restrict__ gamma,
    const float* __restrict__ beta, float* __restrict__ out)
{
    int row = blockIdx.x;
    int t = threadIdx.x;
    const float* x = S + (size_t)row * DMODEL;
    float4 v = *reinterpret_cast<const float4*>(x + t * 4);
    float sum = v.x + v.y + v.z + v.w;
    float sq = v.x * v.x + v.y * v.y + v.z * v.z + v.w * v.w;
    #pragma unroll
    for (int d = 1; d < 64; d <<= 1) { sum += __shfl_xor(sum, d); sq += __shfl_xor(sq, d); }
    __shared__ float ssum[4], ssq[4];
    int w = t >> 6, l = t & 63;
    if (l == 0) { ssum[w] = sum; ssq[w] = sq; }
    __syncthreads();
    sum = ssum[0] + ssum[1] + ssum[2] + ssum[3];
    sq = ssq[0] + ssq[1] + ssq[2] + ssq[3];
    float mu = sum / DMODEL;
    float var = sq / DMODEL - mu * mu;
    float inv = rsqrtf(var + LN_EPS);
    float4 g = *reinterpret_cast<const float4*>(gamma + t * 4);
    float4 b = *reinterpret_cast<const float4*>(beta + t * 4);
    float4 o;
    o.x = (v.x - mu) * inv * g.x + b.x;
    o.y = (v.y - mu) * inv * g.y + b.y;
    o.z = (v.z - mu) * inv * g.z + b.z;
    o.w = (v.w - mu) * inv * g.w + b.w;
    *reinterpret_cast<float4*>(out + (size_t)row * DMODEL + t * 4) = o;
}

extern "C" void kernel_launch(void* const* d_in, const int* in_sizes, int n_in,
                              void* d_out, int out_size, void* d_ws, size_t ws_size,
                              hipStream_t stream) {
    const float* ht   = (const float*)d_in[0];
    const float* mask = (const float*)d_in[1];
    const float* Wq   = (const float*)d_in[2];
    const float* bq   = (const float*)d_in[3];
    const float* Wk   = (const float*)d_in[4];
    const float* bk   = (const float*)d_in[5];
    const float* Wv   = (const float*)d_in[6];
    const float* bv   = (const float*)d_in[7];
    const float* Wd   = (const float*)d_in[8];
    const float* bd   = (const float*)d_in[9];
    const float* gamma= (const float*)d_in[10];
    const float* beta = (const float*)d_in[11];
    float* out = (float*)d_out;

    char* ws = (char*)d_ws;
    const size_t MB = 1024 * 1024;
    unsigned short* Xb  = (unsigned short*)(ws + 0 * MB);   // 4 MB
    unsigned short* Wqb = (unsigned short*)(ws + 4 * MB);   // 2 MB
    unsigned short* Wkb = (unsigned short*)(ws + 6 * MB);
    unsigned short* Wvb = (unsigned short*)(ws + 8 * MB);
    unsigned short* Wdb = (unsigned short*)(ws + 10 * MB);
    unsigned short* Qb  = (unsigned short*)(ws + 12 * MB);  // 4 MB
    unsigned short* Kb  = (unsigned short*)(ws + 16 * MB);
    unsigned short* Vb  = (unsigned short*)(ws + 20 * MB);
    unsigned short* Ctxb= (unsigned short*)(ws + 24 * MB);
    float* Sht          = (float*)(ws + 28 * MB);           // 8 MB (Q/K no longer needed -> could overlap, kept separate)

    cvt_f32_bf16<<<(N_TOK * DMODEL) / 4 / 256, 256, 0, stream>>>(ht, Xb);
    cvt_w<<<dim3((DMODEL * DMODEL) / 4 / 256, 4), 256, 0, stream>>>(Wq, Wk, Wv, Wd, Wqb, Wkb, Wvb, Wdb);

    gemm_qkv<<<dim3(16, 24), 256, 0, stream>>>(Xb, Wqb, Wkb, Wvb, bq, bk, bv, Qb, Kb, Vb);

    attn<<<dim3(N_TOK / 64, NHEAD), 256, 0, stream>>>(Qb, Kb, Vb, mask, Ctxb);

    gemm_dense<<<dim3(16, 8), 256, 0, stream>>>(Ctxb, Wdb, bd, ht, Sht);

    layernorm<<<N_TOK, 256, 0, stream>>>(Sht, gamma, beta, out);
}

// Round 2
// 134.111 us; speedup vs baseline: 1.2757x; 1.2757x over previous
//
#include <hip/hip_runtime.h>
#include <hip/hip_bf16.h>

#define N_TOK 2048
#define DMODEL 1024
#define NHEAD 16
#define DHEAD 64
#define LN_EPS 1e-5f

typedef __attribute__((ext_vector_type(8))) short short8;
typedef __attribute__((ext_vector_type(4))) short s16x4;
typedef __attribute__((ext_vector_type(4))) float f32x4;

__device__ inline unsigned short f2bf(float f) {
    union { float f; unsigned u; } v; v.f = f;
    unsigned r = v.u + 0x7FFF + ((v.u >> 16) & 1);
    return (unsigned short)(r >> 16);
}

__device__ __forceinline__ void gld16(const unsigned short* g, unsigned short* l) {
    __builtin_amdgcn_global_load_lds(
        (const __attribute__((address_space(1))) unsigned int*)g,
        (__attribute__((address_space(3))) unsigned int*)l, 16, 0, 0);
}

// ---------------- convert f32 -> bf16 ----------------
__global__ void cvt_f32_bf16(const float* __restrict__ in, unsigned short* __restrict__ out) {
    int i = (blockIdx.x * blockDim.x + threadIdx.x) * 4;
    float4 v = *reinterpret_cast<const float4*>(in + i);
    ushort4 o;
    o.x = f2bf(v.x); o.y = f2bf(v.y); o.z = f2bf(v.z); o.w = f2bf(v.w);
    *reinterpret_cast<ushort4*>(out + i) = o;
}

__global__ void cvt_w(const float* __restrict__ w0, const float* __restrict__ w1,
                      const float* __restrict__ w2, const float* __restrict__ w3,
                      unsigned short* __restrict__ o0, unsigned short* __restrict__ o1,
                      unsigned short* __restrict__ o2, unsigned short* __restrict__ o3) {
    int z = blockIdx.y;
    const float* in = z == 0 ? w0 : (z == 1 ? w1 : (z == 2 ? w2 : w3));
    unsigned short* out = z == 0 ? o0 : (z == 1 ? o1 : (z == 2 ? o2 : o3));
    int i = (blockIdx.x * blockDim.x + threadIdx.x) * 4;
    float4 v = *reinterpret_cast<const float4*>(in + i);
    ushort4 o;
    o.x = f2bf(v.x); o.y = f2bf(v.y); o.z = f2bf(v.z); o.w = f2bf(v.w);
    *reinterpret_cast<ushort4*>(out + i) = o;
}

// ---------------- V transpose: VT[d][n] = V[n][d] ----------------
__global__ __launch_bounds__(256) void vtrans(const unsigned short* __restrict__ V,
                                              unsigned short* __restrict__ VT) {
    __shared__ unsigned short tile[64][72];
    int n0 = blockIdx.x * 64;
    int d0 = blockIdx.y * 64;
    int t = threadIdx.x;
    int r = t >> 3, c8 = t & 7;
    #pragma unroll
    for (int it = 0; it < 2; ++it) {
        int rr = it * 32 + r;
        short8 v = *reinterpret_cast<const short8*>(V + (size_t)(n0 + rr) * DMODEL + d0 + c8 * 8);
        *reinterpret_cast<short8*>(&tile[rr][c8 * 8]) = v;
    }
    __syncthreads();
    #pragma unroll
    for (int it = 0; it < 2; ++it) {
        int rr = it * 32 + r;               // output row (d-local)
        short8 o;
        #pragma unroll
        for (int j = 0; j < 8; ++j) o[j] = (short)tile[c8 * 8 + j][rr];
        *reinterpret_cast<short8*>(VT + (size_t)(d0 + rr) * N_TOK + n0 + c8 * 8) = o;
    }
}

// ---------------- fused QKV GEMM (m97 structure) ----------------
// O = X @ W^T + b ; grid (16, 24): col-blocks 0..7 Q, 8..15 K, 16..23 V
__global__ __launch_bounds__(256) void gemm_qkv(
    const unsigned short* __restrict__ X,
    const unsigned short* __restrict__ Wq, const unsigned short* __restrict__ Wk,
    const unsigned short* __restrict__ Wv,
    const float* __restrict__ bq, const float* __restrict__ bk, const float* __restrict__ bv,
    unsigned short* __restrict__ Q, unsigned short* __restrict__ K, unsigned short* __restrict__ V)
{
    __shared__ __align__(16) unsigned short As[128 * 64];
    __shared__ __align__(16) unsigned short Bs[128 * 64];
    int row0 = blockIdx.x * 128;
    int col0 = blockIdx.y * 128;
    int mat = col0 >> 10;
    int wcol0 = col0 & 1023;
    const unsigned short* W = mat == 0 ? Wq : (mat == 1 ? Wk : Wv);
    const float* bias = mat == 0 ? bq : (mat == 1 ? bk : bv);
    unsigned short* O = mat == 0 ? Q : (mat == 1 ? K : V);

    int t = threadIdx.x, w = t >> 6, l = t & 63;
    int lr = l & 15, lk = l >> 4;
    int wr = (w >> 1) * 64, wc = (w & 1) * 64;
    int srow = l >> 3, scol = (l & 7) * 8;

    f32x4 acc[4][4] = {};

    for (int k0 = 0; k0 < DMODEL; k0 += 64) {
        #pragma unroll
        for (int c = 0; c < 4; ++c) {
            int ci = (w << 2) | c;          // 0..15
            int r = (ci << 3) | srow;       // 0..127
            gld16(X + (size_t)(row0 + r) * DMODEL + k0 + scol, As + ci * 512);
            gld16(W + (size_t)(wcol0 + r) * DMODEL + k0 + scol, Bs + ci * 512);
        }
        __syncthreads();
        #pragma unroll
        for (int kk = 0; kk < 64; kk += 32) {
            short8 af[4], bf[4];
            #pragma unroll
            for (int m = 0; m < 4; ++m)
                af[m] = *reinterpret_cast<const short8*>(As + (wr + m * 16 + lr) * 64 + kk + (lk << 3));
            #pragma unroll
            for (int n = 0; n < 4; ++n)
                bf[n] = *reinterpret_cast<const short8*>(Bs + (wc + n * 16 + lr) * 64 + kk + (lk << 3));
            #pragma unroll
            for (int m = 0; m < 4; ++m)
                #pragma unroll
                for (int n = 0; n < 4; ++n)
                    acc[m][n] = __builtin_amdgcn_mfma_f32_16x16x32_bf16(af[m], bf[n], acc[m][n], 0, 0, 0);
        }
        __syncthreads();
    }

    #pragma unroll
    for (int n = 0; n < 4; ++n) {
        int ccol = wcol0 + wc + n * 16 + lr;
        float bia = bias[ccol];
        #pragma unroll
        for (int m = 0; m < 4; ++m) {
            #pragma unroll
            for (int r = 0; r < 4; ++r) {
                int rowg = row0 + wr + m * 16 + lk * 4 + r;
                O[(size_t)rowg * DMODEL + ccol] = f2bf(acc[m][n][r] + bia);
            }
        }
    }
}

// ---------------- flash attention (swapped-QK^T, in-lane softmax) ----------------
// grid (32, 16): blockIdx.x = q block (64 rows), blockIdx.y = head
__global__ __launch_bounds__(256) void attn(
    const unsigned short* __restrict__ Q, const unsigned short* __restrict__ K,
    const unsigned short* __restrict__ VT, const float* __restrict__ mask,
    unsigned short* __restrict__ Ctx)
{
    __shared__ __align__(16) unsigned short Kt[2][4096];   // [buf][64 kv][64 dh] swizzled
    __shared__ __align__(16) unsigned short Vt[2][4096];   // [buf][64 dh][64 kv] swizzled
    __shared__ __align__(16) unsigned short Ps[4][16 * 72];

    int h = blockIdx.y;
    int hb = h * DHEAD;
    int q0 = blockIdx.x * 64;
    int t = threadIdx.x, w = t >> 6, l = t & 63;
    int lr = l & 15, lk = l >> 4;

    // Q fragment (B-operand, [q-row][dh]) — register-resident
    short8 qf[2];
    #pragma unroll
    for (int kk = 0; kk < 2; ++kk)
        qf[kk] = *reinterpret_cast<const short8*>(
            Q + (size_t)(q0 + w * 16 + lr) * DMODEL + hb + kk * 32 + lk * 8);

    f32x4 ctx[4] = {};
    float mrow = -1e30f, lsum = 0.f;
    int cur = 0;

    // prologue stage (tile 0)
    #pragma unroll
    for (int c = 0; c < 2; ++c) {
        int ci = (w << 1) | c;
        int rr = (ci << 3) | (l >> 3);
        int sc = (((l & 7) ^ (rr & 7)) << 3);
        gld16(K + (size_t)(0 + rr) * DMODEL + hb + sc, &Kt[0][ci * 512]);
        gld16(VT + (size_t)(hb + rr) * N_TOK + 0 + sc, &Vt[0][ci * 512]);
    }
    __syncthreads();

    for (int kt = 0; kt < N_TOK / 64; ++kt) {
        int k0 = kt * 64;
        if (kt + 1 < N_TOK / 64) {
            int k0n = k0 + 64;
            #pragma unroll
            for (int c = 0; c < 2; ++c) {
                int ci = (w << 1) | c;
                int rr = (ci << 3) | (l >> 3);
                int sc = (((l & 7) ^ (rr & 7)) << 3);
                gld16(K + (size_t)(k0n + rr) * DMODEL + hb + sc, &Kt[cur ^ 1][ci * 512]);
                gld16(VT + (size_t)(hb + rr) * N_TOK + k0n + sc, &Vt[cur ^ 1][ci * 512]);
            }
        }
        const unsigned short* Kc = &Kt[cur][0];
        const unsigned short* Vc = &Vt[cur][0];

        // S^T = K Q^T : lane holds S[q=lr][k = n*16 + lk*4 + r]
        f32x4 s[4];
        #pragma unroll
        for (int n = 0; n < 4; ++n) {
            f32x4 z = {};
            #pragma unroll
            for (int kk = 0; kk < 2; ++kk) {
                short8 kf = *reinterpret_cast<const short8*>(
                    Kc + (n * 16 + lr) * 64 + ((((kk << 2) | lk) ^ (lr & 7)) << 3));
                z = __builtin_amdgcn_mfma_f32_16x16x32_bf16(kf, qf[kk], z, 0, 0, 0);
            }
            s[n] = z;
        }

        float tm = -1e30f;
        #pragma unroll
        for (int n = 0; n < 4; ++n) {
            f32x4 m4 = *reinterpret_cast<const f32x4*>(mask + k0 + n * 16 + (lk << 2));
            #pragma unroll
            for (int r = 0; r < 4; ++r) {
                s[n][r] = s[n][r] * 0.125f + (1.0f - m4[r]) * -10000.0f;
                tm = fmaxf(tm, s[n][r]);
            }
        }
        tm = fmaxf(tm, __shfl_xor(tm, 16));
        tm = fmaxf(tm, __shfl_xor(tm, 32));
        float mnew = fmaxf(mrow, tm);
        float scale = __expf(mrow - mnew);
        mrow = mnew;

        float ps = 0.f;
        #pragma unroll
        for (int n = 0; n < 4; ++n) {
            s16x4 pk;
            #pragma unroll
            for (int r = 0; r < 4; ++r) {
                float p = __expf(s[n][r] - mrow);
                ps += p;
                pk[r] = (short)f2bf(p);
            }
            *reinterpret_cast<s16x4*>(&Ps[w][lr * 72 + n * 16 + (lk << 2)]) = pk;
        }
        ps += __shfl_xor(ps, 16);
        ps += __shfl_xor(ps, 32);
        lsum = lsum * scale + ps;

        float scq[4];
        #pragma unroll
        for (int r = 0; r < 4; ++r) scq[r] = __shfl(scale, (lk << 2) | r);
        #pragma unroll
        for (int n = 0; n < 4; ++n)
            #pragma unroll
            for (int r = 0; r < 4; ++r) ctx[n][r] *= scq[r];

        // ctx += P @ V
        #pragma unroll
        for (int kk = 0; kk < 2; ++kk) {
            short8 pf = *reinterpret_cast<const short8*>(&Ps[w][lr * 72 + kk * 32 + (lk << 3)]);
            #pragma unroll
            for (int n = 0; n < 4; ++n) {
                short8 vf = *reinterpret_cast<const short8*>(
                    Vc + (n * 16 + lr) * 64 + ((((kk << 2) | lk) ^ (lr & 7)) << 3));
                ctx[n] = __builtin_amdgcn_mfma_f32_16x16x32_bf16(pf, vf, ctx[n], 0, 0, 0);
            }
        }
        __syncthreads();
        cur ^= 1;
    }

    float inv_[4];
    #pragma unroll
    for (int r = 0; r < 4; ++r) inv_[r] = 1.0f / __shfl(lsum, (lk << 2) | r);
    #pragma unroll
    for (int n = 0; n < 4; ++n) {
        #pragma unroll
        for (int r = 0; r < 4; ++r) {
            Ctx[(size_t)(q0 + w * 16 + (lk << 2) + r) * DMODEL + hb + n * 16 + lr] =
                f2bf(ctx[n][r] * inv_[r]);
        }
    }
}

// ---------------- dense + tanh + residual (m97 structure) ----------------
__global__ __launch_bounds__(256) void gemm_dense(
    const unsigned short* __restrict__ X, const unsigned short* __restrict__ W,
    const float* __restrict__ bias, const float* __restrict__ ht,
    float* __restrict__ Sht)
{
    __shared__ __align__(16) unsigned short As[128 * 64];
    __shared__ __align__(16) unsigned short Bs[128 * 64];
    int row0 = blockIdx.x * 128;
    int col0 = blockIdx.y * 128;

    int t = threadIdx.x, w = t >> 6, l = t & 63;
    int lr = l & 15, lk = l >> 4;
    int wr = (w >> 1) * 64, wc = (w & 1) * 64;
    int srow = l >> 3, scol = (l & 7) * 8;

    f32x4 acc[4][4] = {};

    for (int k0 = 0; k0 < DMODEL; k0 += 64) {
        #pragma unroll
        for (int c = 0; c < 4; ++c) {
            int ci = (w << 2) | c;
            int r = (ci << 3) | srow;
            gld16(X + (size_t)(row0 + r) * DMODEL + k0 + scol, As + ci * 512);
            gld16(W + (size_t)(col0 + r) * DMODEL + k0 + scol, Bs + ci * 512);
        }
        __syncthreads();
        #pragma unroll
        for (int kk = 0; kk < 64; kk += 32) {
            short8 af[4], bf[4];
            #pragma unroll
            for (int m = 0; m < 4; ++m)
                af[m] = *reinterpret_cast<const short8*>(As + (wr + m * 16 + lr) * 64 + kk + (lk << 3));
            #pragma unroll
            for (int n = 0; n < 4; ++n)
                bf[n] = *reinterpret_cast<const short8*>(Bs + (wc + n * 16 + lr) * 64 + kk + (lk << 3));
            #pragma unroll
            for (int m = 0; m < 4; ++m)
                #pragma unroll
                for (int n = 0; n < 4; ++n)
                    acc[m][n] = __builtin_amdgcn_mfma_f32_16x16x32_bf16(af[m], bf[n], acc[m][n], 0, 0, 0);
        }
        __syncthreads();
    }

    #pragma unroll
    for (int n = 0; n < 4; ++n) {
        int col = col0 + wc + n * 16 + lr;
        float bia = bias[col];
        #pragma unroll
        for (int m = 0; m < 4; ++m) {
            #pragma unroll
            for (int r = 0; r < 4; ++r) {
                int rowg = row0 + wr + m * 16 + lk * 4 + r;
                float x2 = 2.0f * (acc[m][n][r] + bia);
                float th = 1.0f - 2.0f / (1.0f + __expf(x2));
                Sht[(size_t)rowg * DMODEL + col] = th + ht[(size_t)rowg * DMODEL + col];
            }
        }
    }
}

// ---------------- layernorm ----------------
__global__ __launch_bounds__(256) void layernorm(
    const float* __restrict__ S, const float* __restrict__ gamma,
    const float* __restrict__ beta, float* __restrict__ out)
{
    int row = blockIdx.x;
    int t = threadIdx.x;
    const float* x = S + (size_t)row * DMODEL;
    float4 v = *reinterpret_cast<const float4*>(x + t * 4);
    float sum = v.x + v.y + v.z + v.w;
    float sq = v.x * v.x + v.y * v.y + v.z * v.z + v.w * v.w;
    #pragma unroll
    for (int d = 1; d < 64; d <<= 1) { sum += __shfl_xor(sum, d); sq += __shfl_xor(sq, d); }
    __shared__ float ssum[4], ssq[4];
    int w = t >> 6, l = t & 63;
    if (l == 0) { ssum[w] = sum; ssq[w] = sq; }
    __syncthreads();
    sum = ssum[0] + ssum[1] + ssum[2] + ssum[3];
    sq = ssq[0] + ssq[1] + ssq[2] + ssq[3];
    float mu = sum / DMODEL;
    float var = sq / DMODEL - mu * mu;
    float inv = rsqrtf(var + LN_EPS);
    float4 g = *reinterpret_cast<const float4*>(gamma + t * 4);
    float4 b = *reinterpret_cast<const float4*>(beta + t * 4);
    float4 o;
    o.x = (v.x - mu) * inv * g.x + b.x;
    o.y = (v.y - mu) * inv * g.y + b.y;
    o.z = (v.z - mu) * inv * g.z + b.z;
    o.w = (v.w - mu) * inv * g.w + b.w;
    *reinterpret_cast<float4*>(out + (size_t)row * DMODEL + t * 4) = o;
}

extern "C" void kernel_launch(void* const* d_in, const int* in_sizes, int n_in,
                              void* d_out, int out_size, void* d_ws, size_t ws_size,
                              hipStream_t stream) {
    const float* ht   = (const float*)d_in[0];
    const float* mask = (const float*)d_in[1];
    const float* Wq   = (const float*)d_in[2];
    const float* bq   = (const float*)d_in[3];
    const float* Wk   = (const float*)d_in[4];
    const float* bk   = (const float*)d_in[5];
    const float* Wv   = (const float*)d_in[6];
    const float* bv   = (const float*)d_in[7];
    const float* Wd   = (const float*)d_in[8];
    const float* bd   = (const float*)d_in[9];
    const float* gamma= (const float*)d_in[10];
    const float* beta = (const float*)d_in[11];
    float* out = (float*)d_out;

    char* ws = (char*)d_ws;
    const size_t MB = 1024 * 1024;
    unsigned short* Xb  = (unsigned short*)(ws + 0 * MB);   // 4 MB
    unsigned short* Wqb = (unsigned short*)(ws + 4 * MB);   // 2 MB each
    unsigned short* Wkb = (unsigned short*)(ws + 6 * MB);
    unsigned short* Wvb = (unsigned short*)(ws + 8 * MB);
    unsigned short* Wdb = (unsigned short*)(ws + 10 * MB);
    unsigned short* Qb  = (unsigned short*)(ws + 12 * MB);  // 4 MB
    unsigned short* Kb  = (unsigned short*)(ws + 16 * MB);  // 4 MB
    unsigned short* Vb  = (unsigned short*)(ws + 20 * MB);  // 4 MB
    unsigned short* VTb = (unsigned short*)(ws + 24 * MB);  // 4 MB
    unsigned short* Ctxb= (unsigned short*)(ws + 28 * MB);  // 4 MB
    float* Sht          = (float*)(ws + 12 * MB);           // 8 MB, overlays Qb/Kb (dead after attn)

    cvt_f32_bf16<<<(N_TOK * DMODEL) / 4 / 256, 256, 0, stream>>>(ht, Xb);
    cvt_w<<<dim3((DMODEL * DMODEL) / 4 / 256, 4), 256, 0, stream>>>(Wq, Wk, Wv, Wd, Wqb, Wkb, Wvb, Wdb);

    gemm_qkv<<<dim3(16, 24), 256, 0, stream>>>(Xb, Wqb, Wkb, Wvb, bq, bk, bv, Qb, Kb, Vb);

    vtrans<<<dim3(N_TOK / 64, DMODEL / 64), 256, 0, stream>>>(Vb, VTb);

    attn<<<dim3(N_TOK / 64, NHEAD), 256, 0, stream>>>(Qb, Kb, VTb, mask, Ctxb);

    gemm_dense<<<dim3(16, 8), 256, 0, stream>>>(Ctxb, Wdb, bd, ht, Sht);

    layernorm<<<N_TOK, 256, 0, stream>>>(Sht, gamma, beta, out);
}

// Round 4
// 127.660 us; speedup vs baseline: 1.3401x; 1.0505x over previous
//
#include <hip/hip_runtime.h>
#include <hip/hip_bf16.h>

#define N_TOK 2048
#define DMODEL 1024
#define NHEAD 16
#define DHEAD 64
#define LN_EPS 1e-5f

typedef __attribute__((ext_vector_type(8))) short short8;
typedef __attribute__((ext_vector_type(4))) short s16x4;
typedef __attribute__((ext_vector_type(4))) float f32x4;

__device__ inline unsigned short f2bf(float f) {
    union { float f; unsigned u; } v; v.f = f;
    unsigned r = v.u + 0x7FFF + ((v.u >> 16) & 1);
    return (unsigned short)(r >> 16);
}

__device__ __forceinline__ void gld16(const unsigned short* g, unsigned short* l) {
    __builtin_amdgcn_global_load_lds(
        (const __attribute__((address_space(1))) unsigned int*)g,
        (__attribute__((address_space(3))) unsigned int*)l, 16, 0, 0);
}

// ---------------- convert f32 -> bf16 ----------------
__global__ void cvt_f32_bf16(const float* __restrict__ in, unsigned short* __restrict__ out) {
    int i = (blockIdx.x * blockDim.x + threadIdx.x) * 4;
    float4 v = *reinterpret_cast<const float4*>(in + i);
    ushort4 o;
    o.x = f2bf(v.x); o.y = f2bf(v.y); o.z = f2bf(v.z); o.w = f2bf(v.w);
    *reinterpret_cast<ushort4*>(out + i) = o;
}

__global__ void cvt_w(const float* __restrict__ w0, const float* __restrict__ w1,
                      const float* __restrict__ w2, const float* __restrict__ w3,
                      unsigned short* __restrict__ o0, unsigned short* __restrict__ o1,
                      unsigned short* __restrict__ o2, unsigned short* __restrict__ o3) {
    int z = blockIdx.y;
    const float* in = z == 0 ? w0 : (z == 1 ? w1 : (z == 2 ? w2 : w3));
    unsigned short* out = z == 0 ? o0 : (z == 1 ? o1 : (z == 2 ? o2 : o3));
    int i = (blockIdx.x * blockDim.x + threadIdx.x) * 4;
    float4 v = *reinterpret_cast<const float4*>(in + i);
    ushort4 o;
    o.x = f2bf(v.x); o.y = f2bf(v.y); o.z = f2bf(v.z); o.w = f2bf(v.w);
    *reinterpret_cast<ushort4*>(out + i) = o;
}

// ---------------- additive mask (e-domain) ----------------
__global__ void prep_madd(const float* __restrict__ mask, float* __restrict__ madd) {
    int i = blockIdx.x * blockDim.x + threadIdx.x;
    madd[i] = (1.0f - mask[i]) * -10000.0f;
}

// ---------------- V transpose: VT[d][n] = V[n][d] ----------------
__global__ __launch_bounds__(256) void vtrans(const unsigned short* __restrict__ V,
                                              unsigned short* __restrict__ VT) {
    __shared__ unsigned short tile[64][72];
    int n0 = blockIdx.x * 64;
    int d0 = blockIdx.y * 64;
    int t = threadIdx.x;
    int r = t >> 3, c8 = t & 7;
    #pragma unroll
    for (int it = 0; it < 2; ++it) {
        int rr = it * 32 + r;
        short8 v = *reinterpret_cast<const short8*>(V + (size_t)(n0 + rr) * DMODEL + d0 + c8 * 8);
        *reinterpret_cast<short8*>(&tile[rr][c8 * 8]) = v;
    }
    __syncthreads();
    #pragma unroll
    for (int it = 0; it < 2; ++it) {
        int rr = it * 32 + r;
        short8 o;
        #pragma unroll
        for (int j = 0; j < 8; ++j) o[j] = (short)tile[c8 * 8 + j][rr];
        *reinterpret_cast<short8*>(VT + (size_t)(d0 + rr) * N_TOK + n0 + c8 * 8) = o;
    }
}

// ---------------- fused QKV GEMM (m97 structure) ----------------
__global__ __launch_bounds__(256) void gemm_qkv(
    const unsigned short* __restrict__ X,
    const unsigned short* __restrict__ Wq, const unsigned short* __restrict__ Wk,
    const unsigned short* __restrict__ Wv,
    const float* __restrict__ bq, const float* __restrict__ bk, const float* __restrict__ bv,
    unsigned short* __restrict__ Q, unsigned short* __restrict__ K, unsigned short* __restrict__ V)
{
    __shared__ __align__(16) unsigned short As[128 * 64];
    __shared__ __align__(16) unsigned short Bs[128 * 64];
    int row0 = blockIdx.x * 128;
    int col0 = blockIdx.y * 128;
    int mat = col0 >> 10;
    int wcol0 = col0 & 1023;
    const unsigned short* W = mat == 0 ? Wq : (mat == 1 ? Wk : Wv);
    const float* bias = mat == 0 ? bq : (mat == 1 ? bk : bv);
    unsigned short* O = mat == 0 ? Q : (mat == 1 ? K : V);

    int t = threadIdx.x, w = t >> 6, l = t & 63;
    int lr = l & 15, lk = l >> 4;
    int wr = (w >> 1) * 64, wc = (w & 1) * 64;
    int srow = l >> 3, scol = (l & 7) * 8;

    f32x4 acc[4][4] = {};

    for (int k0 = 0; k0 < DMODEL; k0 += 64) {
        #pragma unroll
        for (int c = 0; c < 4; ++c) {
            int ci = (w << 2) | c;
            int r = (ci << 3) | srow;
            gld16(X + (size_t)(row0 + r) * DMODEL + k0 + scol, As + ci * 512);
            gld16(W + (size_t)(wcol0 + r) * DMODEL + k0 + scol, Bs + ci * 512);
        }
        __syncthreads();
        #pragma unroll
        for (int kk = 0; kk < 64; kk += 32) {
            short8 af[4], bf[4];
            #pragma unroll
            for (int m = 0; m < 4; ++m)
                af[m] = *reinterpret_cast<const short8*>(As + (wr + m * 16 + lr) * 64 + kk + (lk << 3));
            #pragma unroll
            for (int n = 0; n < 4; ++n)
                bf[n] = *reinterpret_cast<const short8*>(Bs + (wc + n * 16 + lr) * 64 + kk + (lk << 3));
            #pragma unroll
            for (int m = 0; m < 4; ++m)
                #pragma unroll
                for (int n = 0; n < 4; ++n)
                    acc[m][n] = __builtin_amdgcn_mfma_f32_16x16x32_bf16(af[m], bf[n], acc[m][n], 0, 0, 0);
        }
        __syncthreads();
    }

    #pragma unroll
    for (int n = 0; n < 4; ++n) {
        int ccol = wcol0 + wc + n * 16 + lr;
        float bia = bias[ccol];
        #pragma unroll
        for (int m = 0; m < 4; ++m) {
            #pragma unroll
            for (int r = 0; r < 4; ++r) {
                int rowg = row0 + wr + m * 16 + lk * 4 + r;
                O[(size_t)rowg * DMODEL + ccol] = f2bf(acc[m][n][r] + bia);
            }
        }
    }
}

// ---------------- flash attention ----------------
// swapped QK^T (lane q=lr), defer-max, lsum via ones-MFMA; e-domain __expf
__global__ __launch_bounds__(256) void attn(
    const unsigned short* __restrict__ Q, const unsigned short* __restrict__ K,
    const unsigned short* __restrict__ VT, const float* __restrict__ madd,
    unsigned short* __restrict__ Ctx)
{
    __shared__ __align__(16) unsigned short Kt[2][4096];   // [buf][64 kv][64 dh] swizzled
    __shared__ __align__(16) unsigned short Vt[2][4096];   // [buf][64 dh][64 kv] swizzled
    __shared__ __align__(16) unsigned short Ps[4][16 * 72];

    int h = blockIdx.y;
    int hb = h * DHEAD;
    int q0 = blockIdx.x * 64;
    int t = threadIdx.x, w = t >> 6, l = t & 63;
    int lr = l & 15, lk = l >> 4;

    short8 qf[2];
    #pragma unroll
    for (int kk = 0; kk < 2; ++kk)
        qf[kk] = *reinterpret_cast<const short8*>(
            Q + (size_t)(q0 + w * 16 + lr) * DMODEL + hb + kk * 32 + lk * 8);

    short8 ones8;
    #pragma unroll
    for (int j = 0; j < 8; ++j) ones8[j] = (short)0x3F80;  // bf16 1.0

    f32x4 ctx[4] = {};
    f32x4 ctxS = {};           // row-sum accumulator (ℓ), rescaled like ctx
    float mrow = -1e30f;
    int cur = 0;

    #pragma unroll
    for (int c = 0; c < 2; ++c) {
        int ci = (w << 1) | c;
        int rr = (ci << 3) | (l >> 3);
        int sc = (((l & 7) ^ (rr & 7)) << 3);
        gld16(K + (size_t)rr * DMODEL + hb + sc, &Kt[0][ci * 512]);
        gld16(VT + (size_t)(hb + rr) * N_TOK + sc, &Vt[0][ci * 512]);
    }
    __syncthreads();

    for (int kt = 0; kt < N_TOK / 64; ++kt) {
        int k0 = kt * 64;
        if (kt + 1 < N_TOK / 64) {
            int k0n = k0 + 64;
            #pragma unroll
            for (int c = 0; c < 2; ++c) {
                int ci = (w << 1) | c;
                int rr = (ci << 3) | (l >> 3);
                int sc = (((l & 7) ^ (rr & 7)) << 3);
                gld16(K + (size_t)(k0n + rr) * DMODEL + hb + sc, &Kt[cur ^ 1][ci * 512]);
                gld16(VT + (size_t)(hb + rr) * N_TOK + k0n + sc, &Vt[cur ^ 1][ci * 512]);
            }
        }
        const unsigned short* Kc = &Kt[cur][0];
        const unsigned short* Vc = &Vt[cur][0];

        // S^T = K Q^T : lane holds S[q=lr][k = n*16 + lk*4 + r]
        f32x4 s[4];
        __builtin_amdgcn_s_setprio(1);
        #pragma unroll
        for (int n = 0; n < 4; ++n) {
            f32x4 z = {};
            #pragma unroll
            for (int kk = 0; kk < 2; ++kk) {
                short8 kf = *reinterpret_cast<const short8*>(
                    Kc + (n * 16 + lr) * 64 + ((((kk << 2) | lk) ^ (lr & 7)) << 3));
                z = __builtin_amdgcn_mfma_f32_16x16x32_bf16(kf, qf[kk], z, 0, 0, 0);
            }
            s[n] = z;
        }
        __builtin_amdgcn_s_setprio(0);

        float tm = -1e30f;
        #pragma unroll
        for (int n = 0; n < 4; ++n) {
            f32x4 m4 = *reinterpret_cast<const f32x4*>(madd + k0 + n * 16 + (lk << 2));
            #pragma unroll
            for (int r = 0; r < 4; ++r) {
                s[n][r] = fmaf(s[n][r], 0.125f, m4[r]);
                tm = fmaxf(tm, s[n][r]);
            }
        }
        tm = fmaxf(tm, __shfl_xor(tm, 16));
        tm = fmaxf(tm, __shfl_xor(tm, 32));

        if (__any(tm > mrow + 8.0f)) {          // defer-max: rescale only on real growth
            float mnew = fmaxf(mrow, tm);
            float scale = __expf(mrow - mnew);
            mrow = mnew;
            float scq[4];
            #pragma unroll
            for (int r = 0; r < 4; ++r) scq[r] = __shfl(scale, (lk << 2) | r);
            #pragma unroll
            for (int n = 0; n < 4; ++n)
                #pragma unroll
                for (int r = 0; r < 4; ++r) ctx[n][r] *= scq[r];
            #pragma unroll
            for (int r = 0; r < 4; ++r) ctxS[r] *= scq[r];
        }

        // P = exp(S - m), pack as bf16 (short-typed store: keeps ds-write/ds-read ordered)
        #pragma unroll
        for (int n = 0; n < 4; ++n) {
            s16x4 pk;
            #pragma unroll
            for (int r = 0; r < 4; ++r) {
                float p = __expf(s[n][r] - mrow);
                pk[r] = (short)f2bf(p);
            }
            *reinterpret_cast<s16x4*>(&Ps[w][lr * 72 + n * 16 + (lk << 2)]) = pk;
        }

        // ctx += P @ V ; ctxS += P @ 1
        __builtin_amdgcn_s_setprio(1);
        #pragma unroll
        for (int kk = 0; kk < 2; ++kk) {
            short8 pf = *reinterpret_cast<const short8*>(&Ps[w][lr * 72 + kk * 32 + (lk << 3)]);
            #pragma unroll
            for (int n = 0; n < 4; ++n) {
                short8 vf = *reinterpret_cast<const short8*>(
                    Vc + (n * 16 + lr) * 64 + ((((kk << 2) | lk) ^ (lr & 7)) << 3));
                ctx[n] = __builtin_amdgcn_mfma_f32_16x16x32_bf16(pf, vf, ctx[n], 0, 0, 0);
            }
            ctxS = __builtin_amdgcn_mfma_f32_16x16x32_bf16(pf, ones8, ctxS, 0, 0, 0);
        }
        __builtin_amdgcn_s_setprio(0);
        __syncthreads();
        cur ^= 1;
    }

    f32x4 inv_;
    #pragma unroll
    for (int r = 0; r < 4; ++r) inv_[r] = 1.0f / ctxS[r];
    #pragma unroll
    for (int n = 0; n < 4; ++n) {
        #pragma unroll
        for (int r = 0; r < 4; ++r) {
            Ctx[(size_t)(q0 + w * 16 + (lk << 2) + r) * DMODEL + hb + n * 16 + lr] =
                f2bf(ctx[n][r] * inv_[r]);
        }
    }
}

// ---------------- dense + tanh + residual (m97 structure) ----------------
__global__ __launch_bounds__(256) void gemm_dense(
    const unsigned short* __restrict__ X, const unsigned short* __restrict__ W,
    const float* __restrict__ bias, const float* __restrict__ ht,
    float* __restrict__ Sht)
{
    __shared__ __align__(16) unsigned short As[128 * 64];
    __shared__ __align__(16) unsigned short Bs[128 * 64];
    int row0 = blockIdx.x * 128;
    int col0 = blockIdx.y * 128;

    int t = threadIdx.x, w = t >> 6, l = t & 63;
    int lr = l & 15, lk = l >> 4;
    int wr = (w >> 1) * 64, wc = (w & 1) * 64;
    int srow = l >> 3, scol = (l & 7) * 8;

    f32x4 acc[4][4] = {};

    for (int k0 = 0; k0 < DMODEL; k0 += 64) {
        #pragma unroll
        for (int c = 0; c < 4; ++c) {
            int ci = (w << 2) | c;
            int r = (ci << 3) | srow;
            gld16(X + (size_t)(row0 + r) * DMODEL + k0 + scol, As + ci * 512);
            gld16(W + (size_t)(col0 + r) * DMODEL + k0 + scol, Bs + ci * 512);
        }
        __syncthreads();
        #pragma unroll
        for (int kk = 0; kk < 64; kk += 32) {
            short8 af[4], bf[4];
            #pragma unroll
            for (int m = 0; m < 4; ++m)
                af[m] = *reinterpret_cast<const short8*>(As + (wr + m * 16 + lr) * 64 + kk + (lk << 3));
            #pragma unroll
            for (int n = 0; n < 4; ++n)
                bf[n] = *reinterpret_cast<const short8*>(Bs + (wc + n * 16 + lr) * 64 + kk + (lk << 3));
            #pragma unroll
            for (int m = 0; m < 4; ++m)
                #pragma unroll
                for (int n = 0; n < 4; ++n)
                    acc[m][n] = __builtin_amdgcn_mfma_f32_16x16x32_bf16(af[m], bf[n], acc[m][n], 0, 0, 0);
        }
        __syncthreads();
    }

    #pragma unroll
    for (int n = 0; n < 4; ++n) {
        int col = col0 + wc + n * 16 + lr;
        float bia = bias[col];
        #pragma unroll
        for (int m = 0; m < 4; ++m) {
            #pragma unroll
            for (int r = 0; r < 4; ++r) {
                int rowg = row0 + wr + m * 16 + lk * 4 + r;
                float x2 = 2.0f * (acc[m][n][r] + bia);
                float th = 1.0f - 2.0f / (1.0f + __expf(x2));
                Sht[(size_t)rowg * DMODEL + col] = th + ht[(size_t)rowg * DMODEL + col];
            }
        }
    }
}

// ---------------- layernorm ----------------
__global__ __launch_bounds__(256) void layernorm(
    const float* __restrict__ S, const float* __restrict__ gamma,
    const float* __restrict__ beta, float* __restrict__ out)
{
    int row = blockIdx.x;
    int t = threadIdx.x;
    const float* x = S + (size_t)row * DMODEL;
    float4 v = *reinterpret_cast<const float4*>(x + t * 4);
    float sum = v.x + v.y + v.z + v.w;
    float sq = v.x * v.x + v.y * v.y + v.z * v.z + v.w * v.w;
    #pragma unroll
    for (int d = 1; d < 64; d <<= 1) { sum += __shfl_xor(sum, d); sq += __shfl_xor(sq, d); }
    __shared__ float ssum[4], ssq[4];
    int w = t >> 6, l = t & 63;
    if (l == 0) { ssum[w] = sum; ssq[w] = sq; }
    __syncthreads();
    sum = ssum[0] + ssum[1] + ssum[2] + ssum[3];
    sq = ssq[0] + ssq[1] + ssq[2] + ssq[3];
    float mu = sum / DMODEL;
    float var = sq / DMODEL - mu * mu;
    float inv = rsqrtf(var + LN_EPS);
    float4 g = *reinterpret_cast<const float4*>(gamma + t * 4);
    float4 b = *reinterpret_cast<const float4*>(beta + t * 4);
    float4 o;
    o.x = (v.x - mu) * inv * g.x + b.x;
    o.y = (v.y - mu) * inv * g.y + b.y;
    o.z = (v.z - mu) * inv * g.z + b.z;
    o.w = (v.w - mu) * inv * g.w + b.w;
    *reinterpret_cast<float4*>(out + (size_t)row * DMODEL + t * 4) = o;
}

extern "C" void kernel_launch(void* const* d_in, const int* in_sizes, int n_in,
                              void* d_out, int out_size, void* d_ws, size_t ws_size,
                              hipStream_t stream) {
    const float* ht   = (const float*)d_in[0];
    const float* mask = (const float*)d_in[1];
    const float* Wq   = (const float*)d_in[2];
    const float* bq   = (const float*)d_in[3];
    const float* Wk   = (const float*)d_in[4];
    const float* bk   = (const float*)d_in[5];
    const float* Wv   = (const float*)d_in[6];
    const float* bv   = (const float*)d_in[7];
    const float* Wd   = (const float*)d_in[8];
    const float* bd   = (const float*)d_in[9];
    const float* gamma= (const float*)d_in[10];
    const float* beta = (const float*)d_in[11];
    float* out = (float*)d_out;

    char* ws = (char*)d_ws;
    const size_t MB = 1024 * 1024;
    unsigned short* Xb  = (unsigned short*)(ws + 0 * MB);   // 4 MB
    unsigned short* Wqb = (unsigned short*)(ws + 4 * MB);   // 2 MB each
    unsigned short* Wkb = (unsigned short*)(ws + 6 * MB);
    unsigned short* Wvb = (unsigned short*)(ws + 8 * MB);
    unsigned short* Wdb = (unsigned short*)(ws + 10 * MB);
    unsigned short* Qb  = (unsigned short*)(ws + 12 * MB);  // 4 MB
    unsigned short* Kb  = (unsigned short*)(ws + 16 * MB);  // 4 MB
    unsigned short* Vb  = (unsigned short*)(ws + 20 * MB);  // 4 MB
    unsigned short* VTb = (unsigned short*)(ws + 24 * MB);  // 4 MB
    unsigned short* Ctxb= (unsigned short*)(ws + 28 * MB);  // 4 MB
    float* maddb        = (float*)(ws + 32 * MB);           // 8 KB
    float* Sht          = (float*)(ws + 12 * MB);           // 8 MB, overlays Qb/Kb (dead after attn)

    cvt_f32_bf16<<<(N_TOK * DMODEL) / 4 / 256, 256, 0, stream>>>(ht, Xb);
    cvt_w<<<dim3((DMODEL * DMODEL) / 4 / 256, 4), 256, 0, stream>>>(Wq, Wk, Wv, Wd, Wqb, Wkb, Wvb, Wdb);
    prep_madd<<<N_TOK / 256, 256, 0, stream>>>(mask, maddb);

    gemm_qkv<<<dim3(16, 24), 256, 0, stream>>>(Xb, Wqb, Wkb, Wvb, bq, bk, bv, Qb, Kb, Vb);

    vtrans<<<dim3(N_TOK / 64, DMODEL / 64), 256, 0, stream>>>(Vb, VTb);

    attn<<<dim3(N_TOK / 64, NHEAD), 256, 0, stream>>>(Qb, Kb, VTb, maddb, Ctxb);

    gemm_dense<<<dim3(16, 8), 256, 0, stream>>>(Ctxb, Wdb, bd, ht, Sht);

    layernorm<<<N_TOK, 256, 0, stream>>>(Sht, gamma, beta, out);
}

// Round 5
// 109.387 us; speedup vs baseline: 1.5640x; 1.1670x over previous
//
#include <hip/hip_runtime.h>
#include <hip/hip_bf16.h>

#define N_TOK 2048
#define DMODEL 1024
#define NHEAD 16
#define DHEAD 64
#define LN_EPS 1e-5f

typedef __attribute__((ext_vector_type(8))) short short8;
typedef __attribute__((ext_vector_type(4))) short s16x4;
typedef __attribute__((ext_vector_type(4))) float f32x4;

__device__ inline unsigned short f2bf(float f) {
    union { float f; unsigned u; } v; v.f = f;
    unsigned r = v.u + 0x7FFF + ((v.u >> 16) & 1);
    return (unsigned short)(r >> 16);
}

__device__ __forceinline__ void gld16(const unsigned short* g, unsigned short* l) {
    __builtin_amdgcn_global_load_lds(
        (const __attribute__((address_space(1))) unsigned int*)g,
        (__attribute__((address_space(3))) unsigned int*)l, 16, 0, 0);
}

// ---------------- merged convert: X, 4 weights -> bf16 ; mask -> madd ----------------
__global__ __launch_bounds__(256) void cvt_all(
    const float* __restrict__ ht, const float* __restrict__ Wq, const float* __restrict__ Wk,
    const float* __restrict__ Wv, const float* __restrict__ Wd, const float* __restrict__ mask,
    unsigned short* __restrict__ Xb, unsigned short* __restrict__ Wqb,
    unsigned short* __restrict__ Wkb, unsigned short* __restrict__ Wvb,
    unsigned short* __restrict__ Wdb, float* __restrict__ madd)
{
    int b = blockIdx.x;
    if (b < 6144) {
        const float* in; unsigned short* out; int off;
        if (b < 2048) { in = ht; out = Xb; off = b * 1024; }
        else {
            int wb = b - 2048; int wi = wb >> 10;
            off = (wb & 1023) * 1024;
            in  = wi == 0 ? Wq  : wi == 1 ? Wk  : wi == 2 ? Wv  : Wd;
            out = wi == 0 ? Wqb : wi == 1 ? Wkb : wi == 2 ? Wvb : Wdb;
        }
        int i = off + threadIdx.x * 4;
        float4 v = *reinterpret_cast<const float4*>(in + i);
        ushort4 o;
        o.x = f2bf(v.x); o.y = f2bf(v.y); o.z = f2bf(v.z); o.w = f2bf(v.w);
        *reinterpret_cast<ushort4*>(out + i) = o;
    } else {
        int i = (b - 6144) * 1024 + threadIdx.x * 4;
        float4 m = *reinterpret_cast<const float4*>(mask + i);
        float4 o;
        o.x = (1.0f - m.x) * -10000.0f;
        o.y = (1.0f - m.y) * -10000.0f;
        o.z = (1.0f - m.z) * -10000.0f;
        o.w = (1.0f - m.w) * -10000.0f;
        *reinterpret_cast<float4*>(madd + i) = o;
    }
}

// ---------------- V transpose: VT[d][n] = V[n][d] ----------------
__global__ __launch_bounds__(256) void vtrans(const unsigned short* __restrict__ V,
                                              unsigned short* __restrict__ VT) {
    __shared__ unsigned short tile[64][72];
    int n0 = blockIdx.x * 64;
    int d0 = blockIdx.y * 64;
    int t = threadIdx.x;
    int r = t >> 3, c8 = t & 7;
    #pragma unroll
    for (int it = 0; it < 2; ++it) {
        int rr = it * 32 + r;
        short8 v = *reinterpret_cast<const short8*>(V + (size_t)(n0 + rr) * DMODEL + d0 + c8 * 8);
        *reinterpret_cast<short8*>(&tile[rr][c8 * 8]) = v;
    }
    __syncthreads();
    #pragma unroll
    for (int it = 0; it < 2; ++it) {
        int rr = it * 32 + r;
        short8 o;
        #pragma unroll
        for (int j = 0; j < 8; ++j) o[j] = (short)tile[c8 * 8 + j][rr];
        *reinterpret_cast<short8*>(VT + (size_t)(d0 + rr) * N_TOK + n0 + c8 * 8) = o;
    }
}

// ---------------- fused QKV GEMM (64x128 tile, m97 staging) ----------------
// grid (32, 24): col-blocks 0..7 Q, 8..15 K, 16..23 V
__global__ __launch_bounds__(256) void gemm_qkv(
    const unsigned short* __restrict__ X,
    const unsigned short* __restrict__ Wq, const unsigned short* __restrict__ Wk,
    const unsigned short* __restrict__ Wv,
    const float* __restrict__ bq, const float* __restrict__ bk, const float* __restrict__ bv,
    unsigned short* __restrict__ Q, unsigned short* __restrict__ K, unsigned short* __restrict__ V)
{
    __shared__ __align__(16) unsigned short As[64 * 64];
    __shared__ __align__(16) unsigned short Bs[128 * 64];
    int row0 = blockIdx.x * 64;
    int col0 = blockIdx.y * 128;
    int mat = col0 >> 10;
    int wcol0 = col0 & 1023;
    const unsigned short* W = mat == 0 ? Wq : (mat == 1 ? Wk : Wv);
    const float* bias = mat == 0 ? bq : (mat == 1 ? bk : bv);
    unsigned short* O = mat == 0 ? Q : (mat == 1 ? K : V);

    int t = threadIdx.x, w = t >> 6, l = t & 63;
    int lr = l & 15, lk = l >> 4;
    int wc = w * 32;
    int srow = l >> 3, scol = (l & 7) * 8;

    f32x4 acc[4][2] = {};

    for (int k0 = 0; k0 < DMODEL; k0 += 64) {
        #pragma unroll
        for (int c = 0; c < 2; ++c) {
            int ci = (w << 1) | c;
            int r = (ci << 3) | srow;
            gld16(X + (size_t)(row0 + r) * DMODEL + k0 + scol, As + ci * 512);
        }
        #pragma unroll
        for (int c = 0; c < 4; ++c) {
            int ci = (w << 2) | c;
            int r = (ci << 3) | srow;
            gld16(W + (size_t)(wcol0 + r) * DMODEL + k0 + scol, Bs + ci * 512);
        }
        __syncthreads();
        #pragma unroll
        for (int kk = 0; kk < 64; kk += 32) {
            short8 af[4], bf[2];
            #pragma unroll
            for (int m = 0; m < 4; ++m)
                af[m] = *reinterpret_cast<const short8*>(As + (m * 16 + lr) * 64 + kk + (lk << 3));
            #pragma unroll
            for (int n = 0; n < 2; ++n)
                bf[n] = *reinterpret_cast<const short8*>(Bs + (wc + n * 16 + lr) * 64 + kk + (lk << 3));
            #pragma unroll
            for (int m = 0; m < 4; ++m)
                #pragma unroll
                for (int n = 0; n < 2; ++n)
                    acc[m][n] = __builtin_amdgcn_mfma_f32_16x16x32_bf16(af[m], bf[n], acc[m][n], 0, 0, 0);
        }
        __syncthreads();
    }

    #pragma unroll
    for (int n = 0; n < 2; ++n) {
        int ccol = wcol0 + wc + n * 16 + lr;
        float bia = bias[ccol];
        #pragma unroll
        for (int m = 0; m < 4; ++m) {
            #pragma unroll
            for (int r = 0; r < 4; ++r) {
                int rowg = row0 + m * 16 + lk * 4 + r;
                O[(size_t)rowg * DMODEL + ccol] = f2bf(acc[m][n][r] + bia);
            }
        }
    }
}

// ---------------- flash attention ----------------
// swapped QK^T (lane q=lr), defer-max, lsum via ones-MFMA, perm-packed P,
// 3-buffer 2-ahead prefetch with counted vmcnt
__global__ __launch_bounds__(256) void attn(
    const unsigned short* __restrict__ Q, const unsigned short* __restrict__ K,
    const unsigned short* __restrict__ VT, const float* __restrict__ madd,
    unsigned short* __restrict__ Ctx)
{
    __shared__ __align__(16) unsigned short Kt[3][4096];   // [buf][64 kv][64 dh] swizzled
    __shared__ __align__(16) unsigned short Vt[3][4096];   // [buf][64 dh][64 kv] swizzled
    __shared__ __align__(16) unsigned short Ps[4][16 * 72];

    int h = blockIdx.y;
    int hb = h * DHEAD;
    int q0 = blockIdx.x * 64;
    int t = threadIdx.x, w = t >> 6, l = t & 63;
    int lr = l & 15, lk = l >> 4;

    short8 qf[2];
    #pragma unroll
    for (int kk = 0; kk < 2; ++kk)
        qf[kk] = *reinterpret_cast<const short8*>(
            Q + (size_t)(q0 + w * 16 + lr) * DMODEL + hb + kk * 32 + lk * 8);

    short8 ones8;
    #pragma unroll
    for (int j = 0; j < 8; ++j) ones8[j] = (short)0x3F80;  // bf16 1.0

    f32x4 ctx[4] = {};
    f32x4 ctxS = {};           // row-sum accumulator (l), rescaled like ctx
    float mrow = -1e30f;

#define STAGE(kt_, buf_) do {                                                   \
        int k0s = (kt_) * 64;                                                   \
        _Pragma("unroll")                                                       \
        for (int c = 0; c < 2; ++c) {                                           \
            int ci = (w << 1) | c;                                              \
            int rr = (ci << 3) | (l >> 3);                                      \
            int sc = (((l & 7) ^ (rr & 7)) << 3);                               \
            gld16(K + (size_t)(k0s + rr) * DMODEL + hb + sc, &Kt[buf_][ci * 512]); \
            gld16(VT + (size_t)(hb + rr) * N_TOK + k0s + sc, &Vt[buf_][ci * 512]); \
        }                                                                       \
    } while (0)

    STAGE(0, 0);
    STAGE(1, 1);
    asm volatile("s_waitcnt vmcnt(4)");
    __builtin_amdgcn_s_barrier();
    __builtin_amdgcn_sched_barrier(0);

    int cb = 0;                // buffer holding tile kt
    for (int kt = 0; kt < N_TOK / 64; ++kt) {
        // mask values first (so compiler's wait on them drains only older DMAs)
        f32x4 m4[4];
        #pragma unroll
        for (int n = 0; n < 4; ++n)
            m4[n] = *reinterpret_cast<const f32x4*>(madd + kt * 64 + n * 16 + (lk << 2));
        __builtin_amdgcn_sched_barrier(0);

        if (kt + 2 < N_TOK / 64) {
            int sb = cb + 2; if (sb >= 3) sb -= 3;
            STAGE(kt + 2, sb);
        }

        const unsigned short* Kc = &Kt[cb][0];
        const unsigned short* Vc = &Vt[cb][0];

        // S^T = K Q^T : lane holds S[q=lr][k = n*16 + lk*4 + r]
        f32x4 s[4];
        __builtin_amdgcn_s_setprio(1);
        #pragma unroll
        for (int n = 0; n < 4; ++n) {
            f32x4 z = {};
            #pragma unroll
            for (int kk = 0; kk < 2; ++kk) {
                short8 kf = *reinterpret_cast<const short8*>(
                    Kc + (n * 16 + lr) * 64 + ((((kk << 2) | lk) ^ (lr & 7)) << 3));
                z = __builtin_amdgcn_mfma_f32_16x16x32_bf16(kf, qf[kk], z, 0, 0, 0);
            }
            s[n] = z;
        }
        __builtin_amdgcn_s_setprio(0);

        float tm = -1e30f;
        #pragma unroll
        for (int n = 0; n < 4; ++n) {
            #pragma unroll
            for (int r = 0; r < 4; ++r) {
                s[n][r] = fmaf(s[n][r], 0.125f, m4[n][r]);
                tm = fmaxf(tm, s[n][r]);
            }
        }
        tm = fmaxf(tm, __shfl_xor(tm, 16));
        tm = fmaxf(tm, __shfl_xor(tm, 32));

        if (__any(tm > mrow + 8.0f)) {          // defer-max: rescale only on real growth
            float mnew = fmaxf(mrow, tm);
            float scale = __expf(mrow - mnew);
            mrow = mnew;
            float scq[4];
            #pragma unroll
            for (int r = 0; r < 4; ++r) scq[r] = __shfl(scale, (lk << 2) | r);
            #pragma unroll
            for (int n = 0; n < 4; ++n)
                #pragma unroll
                for (int r = 0; r < 4; ++r) ctx[n][r] *= scq[r];
            #pragma unroll
            for (int r = 0; r < 4; ++r) ctxS[r] *= scq[r];
        }

        // P = exp(S - m); pack pairs with v_perm_b32 (round-to-nearest via +0x8000)
        #pragma unroll
        for (int n = 0; n < 4; ++n) {
            unsigned pb[4];
            #pragma unroll
            for (int r = 0; r < 4; ++r) {
                float p = __expf(s[n][r] - mrow);
                union { float f; unsigned u; } cv; cv.f = p;
                pb[r] = cv.u + 0x8000u;
            }
            unsigned lo = __builtin_amdgcn_perm(pb[1], pb[0], 0x07060302u);
            unsigned hi = __builtin_amdgcn_perm(pb[3], pb[2], 0x07060302u);
            union { unsigned u[2]; s16x4 v; } pu;
            pu.u[0] = lo; pu.u[1] = hi;
            *reinterpret_cast<s16x4*>(&Ps[w][lr * 72 + n * 16 + (lk << 2)]) = pu.v;
        }

        // ctx += P @ V ; ctxS += P @ 1
        __builtin_amdgcn_s_setprio(1);
        #pragma unroll
        for (int kk = 0; kk < 2; ++kk) {
            short8 pf = *reinterpret_cast<const short8*>(&Ps[w][lr * 72 + kk * 32 + (lk << 3)]);
            #pragma unroll
            for (int n = 0; n < 4; ++n) {
                short8 vf = *reinterpret_cast<const short8*>(
                    Vc + (n * 16 + lr) * 64 + ((((kk << 2) | lk) ^ (lr & 7)) << 3));
                ctx[n] = __builtin_amdgcn_mfma_f32_16x16x32_bf16(pf, vf, ctx[n], 0, 0, 0);
            }
            ctxS = __builtin_amdgcn_mfma_f32_16x16x32_bf16(pf, ones8, ctxS, 0, 0, 0);
        }
        __builtin_amdgcn_s_setprio(0);

        if (kt + 1 < N_TOK / 64) {
            __builtin_amdgcn_sched_barrier(0);
            if (kt + 2 < N_TOK / 64) asm volatile("s_waitcnt vmcnt(4)");
            else                     asm volatile("s_waitcnt vmcnt(0)");
            __builtin_amdgcn_s_barrier();
            __builtin_amdgcn_sched_barrier(0);
        }
        cb = (cb == 2) ? 0 : cb + 1;
    }
#undef STAGE

    f32x4 inv_;
    #pragma unroll
    for (int r = 0; r < 4; ++r) inv_[r] = 1.0f / ctxS[r];
    #pragma unroll
    for (int n = 0; n < 4; ++n) {
        #pragma unroll
        for (int r = 0; r < 4; ++r) {
            Ctx[(size_t)(q0 + w * 16 + (lk << 2) + r) * DMODEL + hb + n * 16 + lr] =
                f2bf(ctx[n][r] * inv_[r]);
        }
    }
}

// ---------------- dense + tanh + residual (64x128 tile) ----------------
__global__ __launch_bounds__(256) void gemm_dense(
    const unsigned short* __restrict__ X, const unsigned short* __restrict__ W,
    const float* __restrict__ bias, const float* __restrict__ ht,
    float* __restrict__ Sht)
{
    __shared__ __align__(16) unsigned short As[64 * 64];
    __shared__ __align__(16) unsigned short Bs[128 * 64];
    int row0 = blockIdx.x * 64;
    int col0 = blockIdx.y * 128;

    int t = threadIdx.x, w = t >> 6, l = t & 63;
    int lr = l & 15, lk = l >> 4;
    int wc = w * 32;
    int srow = l >> 3, scol = (l & 7) * 8;

    f32x4 acc[4][2] = {};

    for (int k0 = 0; k0 < DMODEL; k0 += 64) {
        #pragma unroll
        for (int c = 0; c < 2; ++c) {
            int ci = (w << 1) | c;
            int r = (ci << 3) | srow;
            gld16(X + (size_t)(row0 + r) * DMODEL + k0 + scol, As + ci * 512);
        }
        #pragma unroll
        for (int c = 0; c < 4; ++c) {
            int ci = (w << 2) | c;
            int r = (ci << 3) | srow;
            gld16(W + (size_t)(col0 + r) * DMODEL + k0 + scol, Bs + ci * 512);
        }
        __syncthreads();
        #pragma unroll
        for (int kk = 0; kk < 64; kk += 32) {
            short8 af[4], bf[2];
            #pragma unroll
            for (int m = 0; m < 4; ++m)
                af[m] = *reinterpret_cast<const short8*>(As + (m * 16 + lr) * 64 + kk + (lk << 3));
            #pragma unroll
            for (int n = 0; n < 2; ++n)
                bf[n] = *reinterpret_cast<const short8*>(Bs + (wc + n * 16 + lr) * 64 + kk + (lk << 3));
            #pragma unroll
            for (int m = 0; m < 4; ++m)
                #pragma unroll
                for (int n = 0; n < 2; ++n)
                    acc[m][n] = __builtin_amdgcn_mfma_f32_16x16x32_bf16(af[m], bf[n], acc[m][n], 0, 0, 0);
        }
        __syncthreads();
    }

    #pragma unroll
    for (int n = 0; n < 2; ++n) {
        int col = col0 + wc + n * 16 + lr;
        float bia = bias[col];
        #pragma unroll
        for (int m = 0; m < 4; ++m) {
            #pragma unroll
            for (int r = 0; r < 4; ++r) {
                int rowg = row0 + m * 16 + lk * 4 + r;
                float x2 = 2.0f * (acc[m][n][r] + bia);
                float th = 1.0f - 2.0f / (1.0f + __expf(x2));
                Sht[(size_t)rowg * DMODEL + col] = th + ht[(size_t)rowg * DMODEL + col];
            }
        }
    }
}

// ---------------- layernorm ----------------
__global__ __launch_bounds__(256) void layernorm(
    const float* __restrict__ S, const float* __restrict__ gamma,
    const float* __restrict__ beta, float* __restrict__ out)
{
    int row = blockIdx.x;
    int t = threadIdx.x;
    const float* x = S + (size_t)row * DMODEL;
    float4 v = *reinterpret_cast<const float4*>(x + t * 4);
    float sum = v.x + v.y + v.z + v.w;
    float sq = v.x * v.x + v.y * v.y + v.z * v.z + v.w * v.w;
    #pragma unroll
    for (int d = 1; d < 64; d <<= 1) { sum += __shfl_xor(sum, d); sq += __shfl_xor(sq, d); }
    __shared__ float ssum[4], ssq[4];
    int w = t >> 6, l = t & 63;
    if (l == 0) { ssum[w] = sum; ssq[w] = sq; }
    __syncthreads();
    sum = ssum[0] + ssum[1] + ssum[2] + ssum[3];
    sq = ssq[0] + ssq[1] + ssq[2] + ssq[3];
    float mu = sum / DMODEL;
    float var = sq / DMODEL - mu * mu;
    float inv = rsqrtf(var + LN_EPS);
    float4 g = *reinterpret_cast<const float4*>(gamma + t * 4);
    float4 b = *reinterpret_cast<const float4*>(beta + t * 4);
    float4 o;
    o.x = (v.x - mu) * inv * g.x + b.x;
    o.y = (v.y - mu) * inv * g.y + b.y;
    o.z = (v.z - mu) * inv * g.z + b.z;
    o.w = (v.w - mu) * inv * g.w + b.w;
    *reinterpret_cast<float4*>(out + (size_t)row * DMODEL + t * 4) = o;
}

extern "C" void kernel_launch(void* const* d_in, const int* in_sizes, int n_in,
                              void* d_out, int out_size, void* d_ws, size_t ws_size,
                              hipStream_t stream) {
    const float* ht   = (const float*)d_in[0];
    const float* mask = (const float*)d_in[1];
    const float* Wq   = (const float*)d_in[2];
    const float* bq   = (const float*)d_in[3];
    const float* Wk   = (const float*)d_in[4];
    const float* bk   = (const float*)d_in[5];
    const float* Wv   = (const float*)d_in[6];
    const float* bv   = (const float*)d_in[7];
    const float* Wd   = (const float*)d_in[8];
    const float* bd   = (const float*)d_in[9];
    const float* gamma= (const float*)d_in[10];
    const float* beta = (const float*)d_in[11];
    float* out = (float*)d_out;

    char* ws = (char*)d_ws;
    const size_t MB = 1024 * 1024;
    unsigned short* Xb  = (unsigned short*)(ws + 0 * MB);   // 4 MB
    unsigned short* Wqb = (unsigned short*)(ws + 4 * MB);   // 2 MB each
    unsigned short* Wkb = (unsigned short*)(ws + 6 * MB);
    unsigned short* Wvb = (unsigned short*)(ws + 8 * MB);
    unsigned short* Wdb = (unsigned short*)(ws + 10 * MB);
    unsigned short* Qb  = (unsigned short*)(ws + 12 * MB);  // 4 MB
    unsigned short* Kb  = (unsigned short*)(ws + 16 * MB);  // 4 MB
    unsigned short* Vb  = (unsigned short*)(ws + 20 * MB);  // 4 MB
    unsigned short* VTb = (unsigned short*)(ws + 24 * MB);  // 4 MB
    unsigned short* Ctxb= (unsigned short*)(ws + 28 * MB);  // 4 MB
    float* maddb        = (float*)(ws + 32 * MB);           // 8 KB
    float* Sht          = (float*)(ws + 12 * MB);           // 8 MB, overlays Qb/Kb (dead after attn)

    cvt_all<<<6146, 256, 0, stream>>>(ht, Wq, Wk, Wv, Wd, mask,
                                      Xb, Wqb, Wkb, Wvb, Wdb, maddb);

    gemm_qkv<<<dim3(32, 24), 256, 0, stream>>>(Xb, Wqb, Wkb, Wvb, bq, bk, bv, Qb, Kb, Vb);

    vtrans<<<dim3(N_TOK / 64, DMODEL / 64), 256, 0, stream>>>(Vb, VTb);

    attn<<<dim3(N_TOK / 64, NHEAD), 256, 0, stream>>>(Qb, Kb, VTb, maddb, Ctxb);

    gemm_dense<<<dim3(32, 8), 256, 0, stream>>>(Ctxb, Wdb, bd, ht, Sht);

    layernorm<<<N_TOK, 256, 0, stream>>>(Sht, gamma, beta, out);
}